// Round 5
// baseline (80.774 us; speedup 1.0000x reference)
//
#include <hip/hip_runtime.h>
#include <math.h>

// ECT layer: ect[b,t,r] = sum_{n: batch[n]==b} sigmoid(8*(lin[r] - <x_n,v_t>))
// N=100000, D=3, T=64, R=64, B=128, lin = linspace(-1.1,1.1,64), d = 2.2/63.
//
// Algorithm (validated in round 4): CIC-deposit nh onto a lin-aligned grid
// (160 bins + 63 zero-pad), then convolve with the exact sigmoid table
// (148 taps). Linear-interp error <= sig''max*d^2/8 ~ 9.4e-4/node << thresh.
//
// Round-4 post-mortem: correct algorithm, latency-bound structure (512 blocks
// = 2 waves/SIMD, long per-wave loops, per-iteration exposed load latency ->
// VALUBusy 4.7%). This round: 2048 blocks (8/CU), block = (b, 4 directions),
// batched node preload (4 independent loads, one wait), tiny per-thread
// loops. One dispatch, no ws, no memset, no global atomics.

#define THREADS 256
#define TPB 4            // directions per block
#define TQ  16           // blocks per point cloud: TPB*TQ = 64 directions
#define ROWLEN 224       // hist row stride (16B-aligned), 63 pad + 160 bins + 1
#define PAD 63
#define WRN 160          // sigmoid taps generated (STEPS+3 used)
#define STEPS 148        // conv taps: out[r] = sum_{j<148} Wr[j]*H[r+j]

#if __has_builtin(__builtin_amdgcn_exp2f)
#define EXP2F(x) __builtin_amdgcn_exp2f(x)
#else
#define EXP2F(x) exp2f(x)
#endif
#if __has_builtin(__builtin_amdgcn_rcpf)
#define RCPF(x) __builtin_amdgcn_rcpf(x)
#else
#define RCPF(x) (1.0f / (x))
#endif

// all-lane 64-ary lower_bound: first i with A[i] >= val (A ascending).
__device__ __forceinline__ int lb64(const int* __restrict__ A, int n, int val,
                                    int lane) {
    int lo = 0, hi = n;
    while (hi - lo > 64) {
        const long long span = hi - lo;
        const int p = lo + (int)((span * lane) >> 6);        // p0 = lo
        const unsigned long long m = __ballot(A[p] < val);   // contiguous ones
        const int c = __popcll(m);
        if (c == 0) { hi = lo; break; }                      // A[lo] >= val
        const int plast = lo + (int)((span * (c - 1)) >> 6);
        const int pnext = (c < 64) ? (lo + (int)((span * (long long)c) >> 6)) : hi;
        lo = plast + 1; hi = pnext;
    }
    const int span = hi - lo;
    const unsigned long long m = __ballot(lane < span && A[lo + lane] < val);
    return lo + __popcll(m);
}

__global__ __launch_bounds__(THREADS, 8) void ect_fused2_kernel(
    const float* __restrict__ x,      // [N,3]
    const float* __restrict__ v,      // [3,64]
    const int*   __restrict__ batch,  // [N] sorted 0..127
    float* __restrict__ out,          // [128,64,64]
    int n, float inv_d, float bias, float negd8l2e)  // -8*d*log2(e)
{
    __shared__ float smem[TPB * ROWLEN + WRN];   // 1056 floats = 4224 B
    float* Wr = smem + TPB * ROWLEN;             // 16B-aligned (896*4 % 16 == 0)

    const int tid  = threadIdx.x;
    const int lane = tid & 63;
    const int b    = blockIdx.x >> 4;            // / TQ
    const int tq   = blockIdx.x & (TQ - 1);

    // zero hist rows (float4, aligned)
    {
        float4* z = (float4*)smem;
        for (int i = tid; i < (TPB * ROWLEN) / 4; i += THREADS)
            z[i] = make_float4(0.f, 0.f, 0.f, 0.f);
    }
    // sigmoid tap table: Wr[j] = sigmoid(8*d*(111-j)) (exact at grid points)
    for (int i = tid; i < WRN; i += THREADS)
        Wr[i] = RCPF(1.0f + EXP2F((float)(111 - i) * negd8l2e));

    // segment bounds (all waves duplicate; overlaps with init)
    const int s0 = lb64(batch, n, b, lane);
    const int s1 = lb64(batch, n, b + 1, lane);

    // direction vectors for this block's 4 t's (wave-uniform values)
    const int tbase = tq * TPB;
    float va[TPB], vb[TPB], vc[TPB];
#pragma unroll
    for (int t = 0; t < TPB; ++t) {
        va[t] = v[tbase + t];
        vb[t] = v[64 + tbase + t];
        vc[t] = v[128 + tbase + t];
    }

    __syncthreads();

    // ---- phase 1: CIC deposit, 1024-node chunks, batched preload ----
    for (int base = s0; base < s1; base += 4 * THREADS) {
        float xs0[4], xs1[4], xs2[4];
        bool  ok[4];
#pragma unroll
        for (int k = 0; k < 4; ++k) {
            const int idx = base + k * THREADS + tid;
            ok[k] = (idx < s1);
            if (ok[k]) {
                const float3 xx = *(const float3*)(x + 3 * (size_t)idx);
                xs0[k] = xx.x; xs1[k] = xx.y; xs2[k] = xx.z;
            }
        }
#pragma unroll
        for (int k = 0; k < 4; ++k) {
            if (!ok[k]) continue;
#pragma unroll
            for (int t = 0; t < TPB; ++t) {
                const float nh = fmaf(xs0[k], va[t], fmaf(xs1[k], vb[t], xs2[k] * vc[t]));
                float bin = fmaf(nh, inv_d, bias);           // (nh - umin)/d
                bin = fminf(fmaxf(bin, 0.0f), 158.999f);     // tails saturate
                const float g0f = floorf(bin);
                const float fr  = bin - g0f;
                const int   g0  = (int)g0f;
                float* Hrow = smem + t * ROWLEN + PAD;
                atomicAdd(Hrow + g0,     1.0f - fr);         // ds_add_f32
                atomicAdd(Hrow + g0 + 1, fr);
            }
        }
    }

    __syncthreads();

    // ---- phase 2: conv. wave w -> direction row w; lane -> r ----
    const int w = tid >> 6;
    const int r = lane;
    const float* H = smem + w * ROWLEN;   // padded row base
    float a0 = 0.f, a1 = 0.f, a2 = 0.f, a3 = 0.f;
#pragma unroll 4
    for (int j = 0; j < STEPS; j += 4) {
        const float4 q = *(const float4*)(Wr + j);   // uniform, aligned
        a0 = fmaf(q.x, H[r + j],     a0);
        a1 = fmaf(q.y, H[r + j + 1], a1);
        a2 = fmaf(q.z, H[r + j + 2], a2);
        a3 = fmaf(q.w, H[r + j + 3], a3);
    }
    out[((size_t)b * 64 + tbase + w) * 64 + r] = (a0 + a1) + (a2 + a3);
}

extern "C" void kernel_launch(void* const* d_in, const int* in_sizes, int n_in,
                              void* d_out, int out_size, void* d_ws, size_t ws_size,
                              hipStream_t stream) {
    const float* x     = (const float*)d_in[0];
    const float* v     = (const float*)d_in[1];
    const int*   batch = (const int*)d_in[2];
    float*       out   = (float*)d_out;

    const int n = in_sizes[0] / 3;

    const double d = 2.2 / 63.0;
    const float inv_d    = (float)(1.0 / d);          // 28.63636...
    const float bias     = 79.5f;                     // 31.5 + 48, exact
    const float negd8l2e = (float)(-8.0 * d * 1.4426950408889634);

    hipLaunchKernelGGL(ect_fused2_kernel, dim3(128 * TQ), dim3(THREADS), 0,
                       stream, x, v, batch, out, n, inv_d, bias, negd8l2e);
}

// Round 6
// 80.272 us; speedup vs baseline: 1.0063x; 1.0063x over previous
//
#include <hip/hip_runtime.h>
#include <math.h>

// ECT layer: ect[b,t,r] = sum_{n: batch[n]==b} sigmoid(8*(lin[r] - <x_n,v_t>))
// N=100000, D=3, T=64, R=64, B=128, lin = linspace(-1.1,1.1,64), d = 2.2/63.
//
// Algorithm (validated r4/r5): CIC-deposit nh onto a lin-aligned grid
// (160 bins + 63 pad), convolve with exact sigmoid table (148 taps).
//
// Round-5 post-mortem: r4 and r5 walls identical (~77-80us) across a 3.5x
// occupancy change -> the invariant is the 12.8M ds_add_f32 deposits, which
// in BOTH rounds had all 64 lanes of each atomic instruction hitting ONE
// histogram row with Gaussian-clustered bins (same-address multiplicity ~4,
// ~236cy/instr back-computed = atomic RMW serialization). This round changes
// ONLY the deposit mapping: lane = (dir, slot) = 4 dirs x 16 node-slots ->
// each instruction spreads over 4 rows x 16 samples (multiplicity ~1), and
// row stride 225 (odd) staggers row base banks. Everything else unchanged.

#define THREADS 256
#define TPB 4            // directions per block
#define TQ  16           // blocks per point cloud: TPB*TQ = 64 directions
#define ROWLEN 225       // hist row stride: 63 pad + 160 bins + 2 spare (odd)
#define PAD 63
#define WRN 160          // sigmoid taps generated (STEPS+3 used)
#define STEPS 148        // conv taps: out[r] = sum_{j<148} Wr[j]*H[r+j]

#if __has_builtin(__builtin_amdgcn_exp2f)
#define EXP2F(x) __builtin_amdgcn_exp2f(x)
#else
#define EXP2F(x) exp2f(x)
#endif
#if __has_builtin(__builtin_amdgcn_rcpf)
#define RCPF(x) __builtin_amdgcn_rcpf(x)
#else
#define RCPF(x) (1.0f / (x))
#endif

// all-lane 64-ary lower_bound: first i with A[i] >= val (A ascending).
__device__ __forceinline__ int lb64(const int* __restrict__ A, int n, int val,
                                    int lane) {
    int lo = 0, hi = n;
    while (hi - lo > 64) {
        const long long span = hi - lo;
        const int p = lo + (int)((span * lane) >> 6);        // p0 = lo
        const unsigned long long m = __ballot(A[p] < val);   // contiguous ones
        const int c = __popcll(m);
        if (c == 0) { hi = lo; break; }                      // A[lo] >= val
        const int plast = lo + (int)((span * (c - 1)) >> 6);
        const int pnext = (c < 64) ? (lo + (int)((span * (long long)c) >> 6)) : hi;
        lo = plast + 1; hi = pnext;
    }
    const int span = hi - lo;
    const unsigned long long m = __ballot(lane < span && A[lo + lane] < val);
    return lo + __popcll(m);
}

__global__ __launch_bounds__(THREADS, 8) void ect_fused3_kernel(
    const float* __restrict__ x,      // [N,3]
    const float* __restrict__ v,      // [3,64]
    const int*   __restrict__ batch,  // [N] sorted 0..127
    float* __restrict__ out,          // [128,64,64]
    int n, float inv_d, float bias, float negd8l2e)  // -8*d*log2(e)
{
    __shared__ float Hist[TPB][ROWLEN];          // 4 x 225 floats
    __shared__ __align__(16) float Wr[WRN];      // sigmoid tap table

    const int tid  = threadIdx.x;
    const int wv   = tid >> 6;                   // wave 0..3
    const int lane = tid & 63;
    const int b    = blockIdx.x >> 4;            // / TQ
    const int tq   = blockIdx.x & (TQ - 1);

    // zero hist (scalar; 900 floats / 256 threads ~ 4 ds_writes)
    {
        float* hz = &Hist[0][0];
        for (int i = tid; i < TPB * ROWLEN; i += THREADS) hz[i] = 0.0f;
    }
    // sigmoid tap table: Wr[j] = sigmoid(8*d*(111-j)) (exact at grid points)
    for (int i = tid; i < WRN; i += THREADS)
        Wr[i] = RCPF(1.0f + EXP2F((float)(111 - i) * negd8l2e));

    // segment bounds (each wave duplicates; overlaps with init)
    const int s0 = lb64(batch, n, b, lane);
    const int s1 = lb64(batch, n, b + 1, lane);

    // deposit mapping: lane = (t_l, slot); block covers 64 nodes/iter
    const int t_l  = lane >> 4;                  // direction 0..3 within block
    const int slot = (lane & 15) + (wv << 4);    // node slot 0..63 across waves
    const int tbase = tq * TPB;
    const int t    = tbase + t_l;
    const float va = v[t], vb = v[64 + t], vc = v[128 + t];

    __syncthreads();

    // ---- phase 1: CIC deposit, one (node, dir) per lane per iteration ----
    for (int base = s0; base < s1; base += 64) {
        const int idx = base + slot;
        if (idx < s1) {
            const float3 xx = *(const float3*)(x + 3 * (size_t)idx);
            const float nh = fmaf(xx.x, va, fmaf(xx.y, vb, xx.z * vc));
            float bin = fmaf(nh, inv_d, bias);           // (nh - umin)/d
            bin = fminf(fmaxf(bin, 0.0f), 158.999f);     // tails saturate
            const float g0f = floorf(bin);
            const float fr  = bin - g0f;
            const int   g0  = (int)g0f;
            atomicAdd(&Hist[t_l][PAD + g0],     1.0f - fr);   // ds_add_f32
            atomicAdd(&Hist[t_l][PAD + g0 + 1], fr);
        }
    }

    __syncthreads();

    // ---- phase 2: conv. wave w -> direction row w; lane -> r ----
    const float* H = &Hist[wv][0];
    const int r = lane;
    float a0 = 0.f, a1 = 0.f, a2 = 0.f, a3 = 0.f;
#pragma unroll 4
    for (int j = 0; j < STEPS; j += 4) {
        const float4 q = *(const float4*)(&Wr[j]);   // uniform, aligned
        a0 = fmaf(q.x, H[r + j],     a0);
        a1 = fmaf(q.y, H[r + j + 1], a1);
        a2 = fmaf(q.z, H[r + j + 2], a2);
        a3 = fmaf(q.w, H[r + j + 3], a3);
    }
    out[((size_t)b * 64 + tbase + wv) * 64 + r] = (a0 + a1) + (a2 + a3);
}

extern "C" void kernel_launch(void* const* d_in, const int* in_sizes, int n_in,
                              void* d_out, int out_size, void* d_ws, size_t ws_size,
                              hipStream_t stream) {
    const float* x     = (const float*)d_in[0];
    const float* v     = (const float*)d_in[1];
    const int*   batch = (const int*)d_in[2];
    float*       out   = (float*)d_out;

    const int n = in_sizes[0] / 3;

    const double d = 2.2 / 63.0;
    const float inv_d    = (float)(1.0 / d);          // 28.63636...
    const float bias     = 79.5f;                     // 31.5 + 48, exact
    const float negd8l2e = (float)(-8.0 * d * 1.4426950408889634);

    hipLaunchKernelGGL(ect_fused3_kernel, dim3(128 * TQ), dim3(THREADS), 0,
                       stream, x, v, batch, out, n, inv_d, bias, negd8l2e);
}

// Round 7
// 19.698 us; speedup vs baseline: 4.1006x; 4.0751x over previous
//
#include <hip/hip_runtime.h>
#include <math.h>

// ECT layer: ect[b,t,r] = sum_{n: batch[n]==b} sigmoid(8*(lin[r] - <x_n,v_t>))
// N=100000, D=3, T=64, R=64, B=128, lin = linspace(-1.1,1.1,64), d = 2.2/63.
//
// Algorithm (validated r4-r6): CIC-deposit nh onto a lin-aligned grid
// (160 bins + 63 pad), convolve with exact sigmoid table (148 taps).
//
// Round-6 post-mortem: r4/r5/r6 walls identical (~78us) across occupancy and
// atomic-address-pattern changes; the invariant is 12.8M ds_add_f32 atomics
// = 50k/CU = 3.7 cy/lane-atomic regardless of pattern -> theory: f32 LDS
// atomics serialize per-lane through a slow FP-RMW path (bank parallelism
// does not apply). This round: ONE change - deposits become fixed-point
// ds_add_u32 (q1 = round(fr*65536), q0 = 65536-q1; 2^-16 folded into the tap
// table; in-place u32->f32 conversion before the unchanged conv phase).
// Integer LDS atomics are classically in-bank/full-rate. Quantization error
// <= 780*0.5/65536 ~ 0.006 << threshold.

#define THREADS 256
#define TPB 4            // directions per block
#define TQ  16           // blocks per point cloud: TPB*TQ = 64 directions
#define ROWLEN 225       // hist row stride: 63 pad + 160 bins + 2 spare (odd)
#define PAD 63
#define WRN 160          // sigmoid taps generated (STEPS+3 used)
#define STEPS 148        // conv taps: out[r] = sum_{j<148} Wr[j]*H[r+j]

#if __has_builtin(__builtin_amdgcn_exp2f)
#define EXP2F(x) __builtin_amdgcn_exp2f(x)
#else
#define EXP2F(x) exp2f(x)
#endif
#if __has_builtin(__builtin_amdgcn_rcpf)
#define RCPF(x) __builtin_amdgcn_rcpf(x)
#else
#define RCPF(x) (1.0f / (x))
#endif

// all-lane 64-ary lower_bound: first i with A[i] >= val (A ascending).
__device__ __forceinline__ int lb64(const int* __restrict__ A, int n, int val,
                                    int lane) {
    int lo = 0, hi = n;
    while (hi - lo > 64) {
        const long long span = hi - lo;
        const int p = lo + (int)((span * lane) >> 6);        // p0 = lo
        const unsigned long long m = __ballot(A[p] < val);   // contiguous ones
        const int c = __popcll(m);
        if (c == 0) { hi = lo; break; }                      // A[lo] >= val
        const int plast = lo + (int)((span * (c - 1)) >> 6);
        const int pnext = (c < 64) ? (lo + (int)((span * (long long)c) >> 6)) : hi;
        lo = plast + 1; hi = pnext;
    }
    const int span = hi - lo;
    const unsigned long long m = __ballot(lane < span && A[lo + lane] < val);
    return lo + __popcll(m);
}

__global__ __launch_bounds__(THREADS, 8) void ect_fused4_kernel(
    const float* __restrict__ x,      // [N,3]
    const float* __restrict__ v,      // [3,64]
    const int*   __restrict__ batch,  // [N] sorted 0..127
    float* __restrict__ out,          // [128,64,64]
    int n, float inv_d, float bias, float negd8l2e)  // -8*d*log2(e)
{
    __shared__ unsigned HistU[TPB][ROWLEN];      // u32 fixed-point histograms
    __shared__ __align__(16) float Wr[WRN];      // sigmoid taps * 2^-16

    float* HistF = (float*)&HistU[0][0];         // f32 view (post-conversion)

    const int tid  = threadIdx.x;
    const int wv   = tid >> 6;                   // wave 0..3
    const int lane = tid & 63;
    const int b    = blockIdx.x >> 4;            // / TQ
    const int tq   = blockIdx.x & (TQ - 1);

    // zero hist
    {
        unsigned* hz = &HistU[0][0];
        for (int i = tid; i < TPB * ROWLEN; i += THREADS) hz[i] = 0u;
    }
    // tap table: Wr[j] = sigmoid(8*d*(111-j)) * 2^-16  (fixed-point unscale)
    for (int i = tid; i < WRN; i += THREADS)
        Wr[i] = RCPF(1.0f + EXP2F((float)(111 - i) * negd8l2e)) * (1.0f / 65536.0f);

    // segment bounds (each wave duplicates; overlaps with init)
    const int s0 = lb64(batch, n, b, lane);
    const int s1 = lb64(batch, n, b + 1, lane);

    // deposit mapping: lane = (t_l, slot); block covers 64 nodes/iter
    const int t_l  = lane >> 4;                  // direction 0..3 within block
    const int slot = (lane & 15) + (wv << 4);    // node slot 0..63 across waves
    const int tbase = tq * TPB;
    const int t    = tbase + t_l;
    const float va = v[t], vb = v[64 + t], vc = v[128 + t];

    __syncthreads();

    // ---- phase 1: CIC deposit (u32 fixed point), one (node,dir)/lane/iter ----
    for (int base = s0; base < s1; base += 64) {
        const int idx = base + slot;
        if (idx < s1) {
            const float3 xx = *(const float3*)(x + 3 * (size_t)idx);
            const float nh = fmaf(xx.x, va, fmaf(xx.y, vb, xx.z * vc));
            float bin = fmaf(nh, inv_d, bias);           // (nh - umin)/d
            bin = fminf(fmaxf(bin, 0.0f), 158.999f);     // tails saturate
            const float g0f = floorf(bin);
            const float fr  = bin - g0f;
            const int   g0  = (int)g0f;
            const unsigned q1 = (unsigned)(fr * 65536.0f + 0.5f);
            const unsigned q0 = 65536u - q1;
            atomicAdd(&HistU[t_l][PAD + g0],     q0);    // ds_add_u32
            atomicAdd(&HistU[t_l][PAD + g0 + 1], q1);
        }
    }

    __syncthreads();

    // ---- phase 1.5: in-place u32 -> f32 conversion ----
    {
        unsigned* hu = &HistU[0][0];
        for (int i = tid; i < TPB * ROWLEN; i += THREADS) {
            const unsigned uv = hu[i];
            HistF[i] = (float)uv;                // scale folded into Wr
        }
    }

    __syncthreads();

    // ---- phase 2: conv. wave w -> direction row w; lane -> r ----
    const float* H = HistF + wv * ROWLEN;
    const int r = lane;
    float a0 = 0.f, a1 = 0.f, a2 = 0.f, a3 = 0.f;
#pragma unroll 4
    for (int j = 0; j < STEPS; j += 4) {
        const float4 q = *(const float4*)(&Wr[j]);   // uniform, aligned
        a0 = fmaf(q.x, H[r + j],     a0);
        a1 = fmaf(q.y, H[r + j + 1], a1);
        a2 = fmaf(q.z, H[r + j + 2], a2);
        a3 = fmaf(q.w, H[r + j + 3], a3);
    }
    out[((size_t)b * 64 + tbase + wv) * 64 + r] = (a0 + a1) + (a2 + a3);
}

extern "C" void kernel_launch(void* const* d_in, const int* in_sizes, int n_in,
                              void* d_out, int out_size, void* d_ws, size_t ws_size,
                              hipStream_t stream) {
    const float* x     = (const float*)d_in[0];
    const float* v     = (const float*)d_in[1];
    const int*   batch = (const int*)d_in[2];
    float*       out   = (float*)d_out;

    const int n = in_sizes[0] / 3;

    const double d = 2.2 / 63.0;
    const float inv_d    = (float)(1.0 / d);          // 28.63636...
    const float bias     = 79.5f;                     // 31.5 + 48, exact
    const float negd8l2e = (float)(-8.0 * d * 1.4426950408889634);

    hipLaunchKernelGGL(ect_fused4_kernel, dim3(128 * TQ), dim3(THREADS), 0,
                       stream, x, v, batch, out, n, inv_d, bias, negd8l2e);
}

// Round 8
// 17.321 us; speedup vs baseline: 4.6633x; 1.1372x over previous
//
#include <hip/hip_runtime.h>
#include <math.h>

// ECT layer: ect[b,t,r] = sum_{n: batch[n]==b} sigmoid(8*(lin[r] - <x_n,v_t>))
// N=100000, D=3, T=64, R=64, B=128, lin = linspace(-1.1,1.1,64), d = 2.2/63.
//
// Algorithm (validated r4-r7): CIC-deposit nh onto a lin-aligned grid
// (160 bins + 63 pad), convolve with exact sigmoid table (148 taps).
// r7 lesson: f32 LDS atomics are a slow serial FP-RMW path on gfx950 ->
// fixed-point ds_add_u32 deposits (4x whole-kernel speedup, validated).
//
// Round-8 changes (conv phase was ~2/3 of remaining wall, LDS-pipe-bound):
//  - sigmoid tap table computed at COMPILE TIME (constexpr exp) -> each
//    tap-FMA is a VOP2 v_fmac_f32 with an inline literal; no LDS tap reads,
//    no per-block table build.
//  - conv loop: 2-tap steps, fully unrolled -> H[r+j],H[r+j+1] merge into
//    one ds_read2_b32 with immediate offsets (single base VGPR).
// Deposit / lb64 / u32->f32 conversion phases unchanged from r7.

#define THREADS 256
#define TPB 4            // directions per block
#define TQ  16           // blocks per point cloud: TPB*TQ = 64 directions
#define ROWLEN 225       // hist row stride: 63 pad + 160 bins + 2 spare (odd)
#define PAD 63
#define STEPS 148        // conv taps: out[r] = sum_{j<148} W[j]*H[r+j]

#if __has_builtin(__builtin_amdgcn_exp2f)
#define EXP2F(x) __builtin_amdgcn_exp2f(x)
#else
#define EXP2F(x) exp2f(x)
#endif
#if __has_builtin(__builtin_amdgcn_rcpf)
#define RCPF(x) __builtin_amdgcn_rcpf(x)
#else
#define RCPF(x) (1.0f / (x))
#endif

// ---- compile-time sigmoid tap table (folded 2^-16 fixed-point unscale) ----
constexpr double cexp_taylor(double r) {
    double s = 1.0, term = 1.0;
    for (int i = 1; i < 18; ++i) { term *= r / (double)i; s += term; }
    return s;
}
constexpr double cexp(double x) {             // |x| < 45
    const double LN2 = 0.69314718055994530942;
    const int n = (int)(x / LN2 + (x >= 0.0 ? 0.5 : -0.5));
    const double r = x - (double)n * LN2;
    double e = cexp_taylor(r);
    if (n >= 0) { for (int i = 0; i < n;  ++i) e *= 2.0; }
    else        { for (int i = 0; i < -n; ++i) e *= 0.5; }
    return e;
}
struct WTab {
    float w[STEPS];
    constexpr WTab() : w() {
        const double d = 2.2 / 63.0;
        for (int j = 0; j < STEPS; ++j) {
            const double z = 8.0 * d * (double)(111 - j);   // sigmoid argument
            w[j] = (float)(1.0 / ((1.0 + cexp(-z)) * 65536.0));
        }
    }
};
constexpr WTab WT;   // WT.w[j] folds as inline literals in unrolled fmas

// all-lane 64-ary lower_bound: first i with A[i] >= val (A ascending).
__device__ __forceinline__ int lb64(const int* __restrict__ A, int n, int val,
                                    int lane) {
    int lo = 0, hi = n;
    while (hi - lo > 64) {
        const long long span = hi - lo;
        const int p = lo + (int)((span * lane) >> 6);        // p0 = lo
        const unsigned long long m = __ballot(A[p] < val);   // contiguous ones
        const int c = __popcll(m);
        if (c == 0) { hi = lo; break; }                      // A[lo] >= val
        const int plast = lo + (int)((span * (c - 1)) >> 6);
        const int pnext = (c < 64) ? (lo + (int)((span * (long long)c) >> 6)) : hi;
        lo = plast + 1; hi = pnext;
    }
    const int span = hi - lo;
    const unsigned long long m = __ballot(lane < span && A[lo + lane] < val);
    return lo + __popcll(m);
}

__global__ __launch_bounds__(THREADS, 8) void ect_fused5_kernel(
    const float* __restrict__ x,      // [N,3]
    const float* __restrict__ v,      // [3,64]
    const int*   __restrict__ batch,  // [N] sorted 0..127
    float* __restrict__ out,          // [128,64,64]
    int n, float inv_d, float bias)
{
    __shared__ unsigned HistU[TPB][ROWLEN];      // u32 fixed-point histograms
    float* HistF = (float*)&HistU[0][0];         // f32 view (post-conversion)

    const int tid  = threadIdx.x;
    const int wv   = tid >> 6;                   // wave 0..3
    const int lane = tid & 63;
    const int b    = blockIdx.x >> 4;            // / TQ
    const int tq   = blockIdx.x & (TQ - 1);

    // zero hist
    {
        unsigned* hz = &HistU[0][0];
        for (int i = tid; i < TPB * ROWLEN; i += THREADS) hz[i] = 0u;
    }

    // segment bounds (each wave duplicates; overlaps with init)
    const int s0 = lb64(batch, n, b, lane);
    const int s1 = lb64(batch, n, b + 1, lane);

    // deposit mapping: lane = (t_l, slot); block covers 64 nodes/iter
    const int t_l  = lane >> 4;                  // direction 0..3 within block
    const int slot = (lane & 15) + (wv << 4);    // node slot 0..63 across waves
    const int tbase = tq * TPB;
    const int t    = tbase + t_l;
    const float va = v[t], vb = v[64 + t], vc = v[128 + t];

    __syncthreads();

    // ---- phase 1: CIC deposit (u32 fixed point), one (node,dir)/lane/iter ----
    for (int base = s0; base < s1; base += 64) {
        const int idx = base + slot;
        if (idx < s1) {
            const float3 xx = *(const float3*)(x + 3 * (size_t)idx);
            const float nh = fmaf(xx.x, va, fmaf(xx.y, vb, xx.z * vc));
            float bin = fmaf(nh, inv_d, bias);           // (nh - umin)/d
            bin = fminf(fmaxf(bin, 0.0f), 158.999f);     // tails saturate
            const float g0f = floorf(bin);
            const float fr  = bin - g0f;
            const int   g0  = (int)g0f;
            const unsigned q1 = (unsigned)(fr * 65536.0f + 0.5f);
            const unsigned q0 = 65536u - q1;
            atomicAdd(&HistU[t_l][PAD + g0],     q0);    // ds_add_u32
            atomicAdd(&HistU[t_l][PAD + g0 + 1], q1);
        }
    }

    __syncthreads();

    // ---- phase 1.5: in-place u32 -> f32 conversion (scale folded in taps) ----
    {
        unsigned* hu = &HistU[0][0];
        for (int i = tid; i < TPB * ROWLEN; i += THREADS)
            HistF[i] = (float)hu[i];
    }

    __syncthreads();

    // ---- phase 2: conv. wave w -> direction row w; lane -> r ----
    const float* H = HistF + wv * ROWLEN + lane;   // single base VGPR
    float a0 = 0.f, a1 = 0.f;
#pragma unroll
    for (int j = 0; j < STEPS; j += 2) {
        a0 = fmaf(WT.w[j],     H[j],     a0);      // literal * ds_read2.lo
        a1 = fmaf(WT.w[j + 1], H[j + 1], a1);      // literal * ds_read2.hi
    }
    out[((size_t)b * 64 + tbase + wv) * 64 + lane] = a0 + a1;
}

extern "C" void kernel_launch(void* const* d_in, const int* in_sizes, int n_in,
                              void* d_out, int out_size, void* d_ws, size_t ws_size,
                              hipStream_t stream) {
    const float* x     = (const float*)d_in[0];
    const float* v     = (const float*)d_in[1];
    const int*   batch = (const int*)d_in[2];
    float*       out   = (float*)d_out;

    const int n = in_sizes[0] / 3;

    const double d = 2.2 / 63.0;
    const float inv_d = (float)(1.0 / d);          // 28.63636...
    const float bias  = 79.5f;                     // 31.5 + 48, exact

    hipLaunchKernelGGL(ect_fused5_kernel, dim3(128 * TQ), dim3(THREADS), 0,
                       stream, x, v, batch, out, n, inv_d, bias);
}